// Round 5
// baseline (330.213 us; speedup 1.0000x reference)
//
#include <hip/hip_runtime.h>
#include <hip/hip_bf16.h>

// ---------- types ----------
typedef __attribute__((ext_vector_type(8))) short short8;   // 8 bf16 (4 VGPR)
typedef __attribute__((ext_vector_type(4))) short short4v;  // 4 bf16
typedef __attribute__((ext_vector_type(4))) float f32x4;

#define B_SZ   512
#define N_BOX  64
#define D_IN   2048
#define D_OUT  1024
#define M_ROWS (B_SZ * N_BOX)   // 32768

__device__ __forceinline__ short f2bf(float x) {
    union { __hip_bfloat16 h; short s; } u;
    u.h = __float2bfloat16(x);
    return u.s;
}
__device__ __forceinline__ float bf2f(short s) {
    union { short s; __hip_bfloat16 h; } u;
    u.s = s;
    return __bfloat162float(u.h);
}

// ---------- 1. W [2048][1024] f32 -> Bt [1024][2048] bf16 ----------
__global__ void transpose_w_kernel(const float* __restrict__ W,
                                   short* __restrict__ Bt) {
    __shared__ float tile[32][33];
    int c0 = blockIdx.x * 32;
    int r0 = blockIdx.y * 32;
    int tc = threadIdx.x & 31;
    int tr = threadIdx.x >> 5;
#pragma unroll
    for (int i = 0; i < 32; i += 8)
        tile[tr + i][tc] = W[(long)(r0 + tr + i) * D_OUT + c0 + tc];
    __syncthreads();
#pragma unroll
    for (int i = 0; i < 32; i += 8)
        Bt[(long)(c0 + tr + i) * D_IN + r0 + tc] = f2bf(tile[tc][tr + i]);
}

// ---------- 2. GEMM: 256x256, BK=64, 4-quarter-phase, A fused f32->bf16 ----------
// LDS map: A at 0   (parity p at p*32768, half h at h*16384)
//          B at 65536 (same sub-layout)
// Swizzle both sides: phys = logical ^ ((row&7)<<4) within a 16 KB half.

// B staging via global_load_lds (bf16 source), inverse-swizzled source.
__device__ __forceinline__ void stage_half_B(const short* __restrict__ mat, long row0, int k0,
                                             char* ldsbase, int tid) {
#pragma unroll
    for (int j = 0; j < 2; ++j) {
        int d = j * 8192 + tid * 16;            // physical byte offset (linear dest)
        int s = d ^ (((d >> 7) & 7) << 4);      // logical
        int row = s >> 7;
        int ke  = (s & 127) >> 1;
        __builtin_amdgcn_global_load_lds(
            (const __attribute__((address_space(1))) void*)(mat + (row0 + row) * D_IN + k0 + ke),
            (__attribute__((address_space(3))) void*)(ldsbase + d), 16, 0, 0);
    }
}

// A staging: 4x global_load_dwordx4 f32 -> regs  (issue-early)
__device__ __forceinline__ void a_load(const float* __restrict__ src, long row0, int k0,
                                       int tid, float4* r) {
    int row = tid >> 2;                 // 0..127
    int kc  = (tid & 3) * 16;           // 0,16,32,48
    const float* p = src + (row0 + row) * D_IN + k0 + kc;
    r[0] = *(const float4*)(p);
    r[1] = *(const float4*)(p + 4);
    r[2] = *(const float4*)(p + 8);
    r[3] = *(const float4*)(p + 12);
}
// ... cvt + 2x swizzled ds_write_b128 (write-late)
__device__ __forceinline__ void a_write(char* half, int tid, const float4* r) {
    int row = tid >> 2;
    int kc2 = (tid & 3) * 32;           // byte col 0,32,64,96
    const float* f = (const float*)r;
    short8 c0, c1;
#pragma unroll
    for (int i = 0; i < 8; ++i) { c0[i] = f2bf(f[i]); c1[i] = f2bf(f[8 + i]); }
    int swz = (row & 7) << 4;
    int b0 = row * 128 + kc2;
    *(short8*)(half + (b0 ^ swz)) = c0;
    *(short8*)(half + ((b0 + 16) ^ swz)) = c1;
}

__device__ __forceinline__ int swz_off(int rowh, int kb) {
    return (rowh * 128 + kb) ^ ((rowh & 7) << 4);
}

#define BAR()    __builtin_amdgcn_s_barrier()
#define SB0()    __builtin_amdgcn_sched_barrier(0)
#define LGKM(n)  do { asm volatile("s_waitcnt lgkmcnt(" #n ")" ::: "memory"); SB0(); } while (0)
#define VMW(n)   do { asm volatile("s_waitcnt vmcnt(" #n ")" ::: "memory"); SB0(); } while (0)

__global__ __launch_bounds__(512, 2)
void gemm256_kernel(const float* __restrict__ A, const short* __restrict__ Bt,
                    const float* __restrict__ bias, short* __restrict__ H) {
    __shared__ char LDS[131072];

    // XCD-bijective swizzle (512 % 8 == 0)
    int bid = blockIdx.x;
    int lid = (bid & 7) * 64 + (bid >> 3);
    int bn = lid & 3;      // 0..3
    int bm = lid >> 2;     // 0..127

    int tid  = threadIdx.x;
    int lane = tid & 63;
    int wave = tid >> 6;
    int wm = wave >> 2;            // A half
    int wn = wave & 3;
    int bh = wn >> 1;              // B half
    int bq = wn & 1;               // B quarter within half
    int lrow = lane & 15;
    int lkb  = (lane >> 4) * 16;

    const long arow0 = (long)bm * 256;
    const long brow0 = (long)bn * 256;

    f32x4 acc[8][4];
#pragma unroll
    for (int i = 0; i < 8; ++i)
#pragma unroll
        for (int j = 0; j < 4; ++j) acc[i][j] = (f32x4)0.0f;

    const int nt = D_IN / 64;   // 32

#define LDF(off) (*(const short8*)(LDS + (off)))
#define READ_AQ(dst, ab, q) do {                                                    \
    _Pragma("unroll") for (int ks = 0; ks < 2; ++ks)                                \
    _Pragma("unroll") for (int f = 0; f < 2; ++f)                                   \
        dst[ks][f] = LDF((ab) + swz_off((q) * 32 + f * 16 + lrow, ks * 64 + lkb)); } while (0)
#define READ_B(dst, bb) do {                                                        \
    _Pragma("unroll") for (int ks = 0; ks < 2; ++ks)                                \
    _Pragma("unroll") for (int nj = 0; nj < 4; ++nj)                                \
        dst[ks][nj] = LDF((bb) + swz_off(nj * 16 + lrow, ks * 64 + lkb)); } while (0)
#define MFMA_Q(q, aq, b) do {                                                       \
    __builtin_amdgcn_s_setprio(1);                                                  \
    _Pragma("unroll") for (int f = 0; f < 2; ++f)                                   \
    _Pragma("unroll") for (int nj = 0; nj < 4; ++nj)                                \
    _Pragma("unroll") for (int ks = 0; ks < 2; ++ks)                                \
        acc[(q) * 2 + f][nj] = __builtin_amdgcn_mfma_f32_16x16x32_bf16(             \
            aq[ks][f], b[ks][nj], acc[(q) * 2 + f][nj], 0, 0, 0);                   \
    __builtin_amdgcn_s_setprio(0); } while (0)

    float4 stA0[4], stA1[4];
    short8 aqW[2][2], aqX[2][2], aqY[2][2], aqZ[2][2];
    short8 bcur[2][4], bnxt[2][4];

    // ---- prologue: A(0) via regs, B(0)+B(1) via gload; leave B(1)x4 in flight
    a_load(A, arow0,       0, tid, stA0);                       // 4 vm
    a_load(A, arow0 + 128, 0, tid, stA1);                       // 4 vm
    stage_half_B(Bt, brow0,       0, LDS + 65536,          tid);// 2 vm
    stage_half_B(Bt, brow0 + 128, 0, LDS + 65536 + 16384,  tid);// 2 vm
    VMW(4);                                 // A(0) done; B(0) in flight
    a_write(LDS,         tid, stA0);
    a_write(LDS + 16384, tid, stA1);
    stage_half_B(Bt, brow0,       64, LDS + 65536 + 32768,         tid);
    stage_half_B(Bt, brow0 + 128, 64, LDS + 65536 + 32768 + 16384, tid);
    VMW(4);                                 // B(0) done; B(1)x4 in flight
    LGKM(0);                                // A writes landed
    BAR(); SB0();
    READ_AQ(aqW, wm * 16384, 0);
    READ_B(bcur, 65536 + bh * 16384 + bq * 8192);
    LGKM(0);

#pragma unroll 1
    for (int t = 0; t < nt; ++t) {
        int par  = (t & 1) * 32768;
        int npar = par ^ 32768;
        int k1 = ((t + 1) & (nt - 1)) * 64;
        int k2 = ((t + 2) & (nt - 1)) * 64;
        int aBase  = par + wm * 16384;
        int aBaseN = npar + wm * 16384;

        // ---- P1: no waits. read aQ1; issue A0(t+1) loads + B0(t+2); MFMA Q0
        READ_AQ(aqX, aBase, 1);
        a_load(A, arow0, k1, tid, stA0);
        stage_half_B(Bt, brow0, k2, LDS + 65536 + par, tid);
        MFMA_Q(0, aqW, bcur);

        // ---- P2: confirm A0 loads; write A0; read aQ2; issue A1 loads + B1(t+2)
        VMW(2);
        a_write(LDS + npar, tid, stA0);
        READ_AQ(aqY, aBase, 2);
        a_load(A, arow0 + 128, k1, tid, stA1);
        stage_half_B(Bt, brow0 + 128, k2, LDS + 65536 + par + 16384, tid);
        LGKM(6);                            // aqX confirmed (writes+aqY remain)
        MFMA_Q(1, aqX, bcur);

        // ---- P3: confirm A1 loads; write A1; read aQ3; publish nbuf
        VMW(2);
        a_write(LDS + npar + 16384, tid, stA1);
        READ_AQ(aqZ, aBase, 3);
        LGKM(4);                            // wrA0+aqY+wrA1 confirmed (aqZ remains)
        MFMA_Q(2, aqY, bcur);
        BAR(); SB0();                       // publish A(t+1) writes + B(t+1) gloads

        // ---- P4: read next-tile B + aQ0 under MFMA Q3
        READ_B(bnxt, 65536 + npar + bh * 16384 + bq * 8192);
        READ_AQ(aqW, aBaseN, 0);
        LGKM(12);                           // aqZ confirmed
        MFMA_Q(3, aqZ, bcur);
        LGKM(0);                            // bnxt + aqW landed
#pragma unroll
        for (int ks = 0; ks < 2; ++ks)
#pragma unroll
            for (int nj = 0; nj < 4; ++nj) bcur[ks][nj] = bnxt[ks][nj];
        BAR(); SB0();                       // tile boundary: bufo free for t+1 writes
    }
#undef LDF

    // ---- epilogue: + bias, ReLU, store bf16.  C/D: col=lane&15, row=(lane>>4)*4+reg
    float bb[4];
#pragma unroll
    for (int nj = 0; nj < 4; ++nj)
        bb[nj] = bias[bn * 256 + wn * 64 + nj * 16 + lrow];
#pragma unroll
    for (int mi = 0; mi < 8; ++mi) {
        long row = arow0 + wm * 128 + mi * 16 + (lane >> 4) * 4;
#pragma unroll
        for (int nj = 0; nj < 4; ++nj) {
            int col = bn * 256 + wn * 64 + nj * 16 + lrow;
#pragma unroll
            for (int r = 0; r < 4; ++r) {
                float v = fmaxf(acc[mi][nj][r] + bb[nj], 0.0f);
                H[(row + r) * D_OUT + col] = f2bf(v);
            }
        }
    }
}

// ---------- 3. LayerNorm + mask-pack (dest-indexed; writes EVERY output row) ----------
__global__ void ln_pack_kernel(const short* __restrict__ H,      // bf16 [32768][1024]
                               const int* __restrict__ mask,     // [512][64]
                               const float* __restrict__ ln_w,
                               const float* __restrict__ ln_b,
                               float* __restrict__ out) {        // [512][64][1024]
    int drow = blockIdx.x;           // destination row (b, j)
    int b = drow >> 6, j = drow & 63;
    int tid = threadIdx.x;
    int lane = tid & 63;
    int wave = tid >> 6;
    int base = tid * 4;

    int mv = mask[(b << 6) | lane];
    unsigned long long bal = __ballot(mv != 0);
    int cnt = __popcll(bal);

    float4 o = make_float4(0.f, 0.f, 0.f, 0.f);
    if (j < cnt) {
        int pre = __popcll(bal & ((1ull << lane) - 1ull));
        unsigned long long sel = __ballot(mv != 0 && pre == j);
        int srcn = (int)__builtin_ctzll(sel);
        long row = (long)((b << 6) | srcn);

        short4v hv = *(const short4v*)(H + row * D_OUT + base);
        float v0 = bf2f(hv[0]), v1 = bf2f(hv[1]), v2 = bf2f(hv[2]), v3 = bf2f(hv[3]);

        float s  = v0 + v1 + v2 + v3;
        float s2 = v0 * v0 + v1 * v1 + v2 * v2 + v3 * v3;
#pragma unroll
        for (int off = 32; off > 0; off >>= 1) {
            s  += __shfl_xor(s, off);
            s2 += __shfl_xor(s2, off);
        }
        __shared__ float red[8];
        if (lane == 0) { red[wave] = s; red[wave + 4] = s2; }
        __syncthreads();
        float S  = red[0] + red[1] + red[2] + red[3];
        float S2 = red[4] + red[5] + red[6] + red[7];
        float mu   = S * (1.0f / D_OUT);
        float var  = S2 * (1.0f / D_OUT) - mu * mu;
        float rstd = rsqrtf(var + 1e-12f);

        float4 wv = *(const float4*)(ln_w + base);
        float4 bv = *(const float4*)(ln_b + base);
        o.x = (v0 - mu) * rstd * wv.x + bv.x;
        o.y = (v1 - mu) * rstd * wv.y + bv.y;
        o.z = (v2 - mu) * rstd * wv.z + bv.z;
        o.w = (v3 - mu) * rstd * wv.w + bv.w;
    }
    *(float4*)(out + (long)drow * D_OUT + base) = o;
}

// ---------- launch ----------
extern "C" void kernel_launch(void* const* d_in, const int* in_sizes, int n_in,
                              void* d_out, int out_size, void* d_ws, size_t ws_size,
                              hipStream_t stream) {
    const float* img  = (const float*)d_in[0];
    const int*   mask = (const int*)d_in[2];
    const float* W    = (const float*)d_in[4];
    const float* bias = (const float*)d_in[5];
    const float* lnw  = (const float*)d_in[6];
    const float* lnb  = (const float*)d_in[7];
    float* out = (float*)d_out;

    short* Bt = (short*)d_ws;                        // 4 MiB
    short* H  = (short*)d_ws + (long)D_OUT * D_IN;   // 64 MiB

    transpose_w_kernel<<<dim3(D_OUT / 32, D_IN / 32), 256, 0, stream>>>(W, Bt);
    gemm256_kernel<<<(M_ROWS / 256) * (D_OUT / 256), 512, 0, stream>>>(img, Bt, bias, H);
    ln_pack_kernel<<<M_ROWS, 256, 0, stream>>>(H, mask, lnw, lnb, out);
}

// Round 6
// 282.773 us; speedup vs baseline: 1.1678x; 1.1678x over previous
//
#include <hip/hip_runtime.h>
#include <hip/hip_bf16.h>

// ---------- types ----------
typedef __attribute__((ext_vector_type(8))) short short8;   // 8 bf16 (4 VGPR)
typedef __attribute__((ext_vector_type(4))) short short4v;  // 4 bf16
typedef __attribute__((ext_vector_type(4))) float f32x4;

#define D_IN   2048
#define D_OUT  1024

__device__ __forceinline__ short f2bf(float x) {
    union { __hip_bfloat16 h; short s; } u;
    u.h = __float2bfloat16(x);
    return u.s;
}

// ---------- 1. W [2048][1024] f32 -> Bt [1024][2048] bf16 ----------
__global__ void transpose_w_kernel(const float* __restrict__ W,
                                   short* __restrict__ Bt) {
    __shared__ float tile[32][33];
    int c0 = blockIdx.x * 32;
    int r0 = blockIdx.y * 32;
    int tc = threadIdx.x & 31;
    int tr = threadIdx.x >> 5;
#pragma unroll
    for (int i = 0; i < 32; i += 8)
        tile[tr + i][tc] = W[(long)(r0 + tr + i) * D_OUT + c0 + tc];
    __syncthreads();
#pragma unroll
    for (int i = 0; i < 32; i += 8)
        Bt[(long)(c0 + tr + i) * D_IN + r0 + tc] = f2bf(tile[tc][tr + i]);
}

// ---------- 2. Fully-fused: GEMM(64x1024x2048) + bias + ReLU + LN + pack ----------
// One block = one image (64 boxes). 512 threads = 8 waves; wave w owns cols
// [w*128, w*128+128). acc[4][8] f32x4 = 128 VGPR.
// LDS: B dbuf 2x64 KiB at 0; A dbuf 2x4 KiB at 131072. Total 139264 B.
// Atom layout (16B atoms): phys_atom = row*4 + (chunk ^ (row&3) ^ ((row>>2)&3))
//  -> b128 frag reads are perfect 2-way (free) on banks; gld source stays
//     64B-contiguous per 4 lanes. Self-inverse, applied on both sides.

#define BAR()    __builtin_amdgcn_s_barrier()
#define SB0()    __builtin_amdgcn_sched_barrier(0)
#define LGKM0()  do { asm volatile("s_waitcnt lgkmcnt(0)" ::: "memory"); SB0(); } while (0)
#define VMW(n)   do { asm volatile("s_waitcnt vmcnt(" #n ")" ::: "memory"); SB0(); } while (0)

__global__ __launch_bounds__(512, 2)
void fused_kernel(const float* __restrict__ img, const short* __restrict__ Bt,
                  const float* __restrict__ bias, const int* __restrict__ mask,
                  const float* __restrict__ lnw, const float* __restrict__ lnb,
                  float* __restrict__ out) {
    __shared__ char LDS[139264];
#define LDSB(buf) (LDS + (buf) * 65536)
#define LDSA(buf) (LDS + 131072 + (buf) * 4096)

    const int b    = blockIdx.x;
    const int tid  = threadIdx.x;
    const int lane = tid & 63;
    const int w    = tid >> 6;
    const int lrow = lane & 15;
    const int lchk = lane >> 4;    // k-chunk 0..3

    // B gld: 8 issues/thread/tile; dest = bufB + i*8192 + tid*16 (linear, required)
    // content at atom p=i*512+tid: row = p>>2 = i*128+(tid>>2); chunk = inv-swz
    const int  bsw   = (tid & 3) ^ ((tid >> 2) & 3) ^ ((tid >> 4) & 3);
    const short* bsrc0 = Bt + (long)(tid >> 2) * D_IN + bsw * 8;
    // A f32 load: row = tid>>3 (0..63), 4 k-elems at (tid&7)*4
    const long arowg = (long)b * 64 + (tid >> 3);
    const int  ak4   = (tid & 7) * 4;
    // A ds_write: half-atom per thread
    const int  arl    = tid >> 3;
    const int  achk   = (tid & 7) >> 1;
    const int  awoff  = (arl * 4 + (achk ^ (arl & 3) ^ ((arl >> 2) & 3))) * 16 + (tid & 1) * 8;
    // frag-read per-lane base: addr = row*64 + fsw + {mi|nf}*1024  (nf-independent swizzle)
    const int  fsw = ((lchk ^ (lrow & 3) ^ ((lrow >> 2) & 3)) << 4);
    const int  afb = lrow * 64 + fsw;
    const int  bfb = w * 8192 + lrow * 64 + fsw;

#define B_GLD(buf, k0) do {                                                         \
    _Pragma("unroll") for (int i = 0; i < 8; ++i)                                   \
        __builtin_amdgcn_global_load_lds(                                           \
            (const __attribute__((address_space(1))) void*)(bsrc0 + (long)i * 128 * D_IN + (k0)), \
            (__attribute__((address_space(3))) void*)(LDSB(buf) + i * 8192 + tid * 16), 16, 0, 0); \
} while (0)
#define A_LOAD(k0)  do { stA = *(const float4*)(img + arowg * D_IN + (k0) + ak4); } while (0)
#define A_WRITE(buf) do {                                                           \
    short4v c_; c_[0] = f2bf(stA.x); c_[1] = f2bf(stA.y);                           \
    c_[2] = f2bf(stA.z); c_[3] = f2bf(stA.w);                                       \
    *(short4v*)(LDSA(buf) + awoff) = c_;                                            \
} while (0)
#define FRAG_READ(fa, fb, abuf, bbuf) do {                                          \
    _Pragma("unroll") for (int mi = 0; mi < 4; ++mi)                                \
        fa[mi] = *(const short8*)((abuf) + afb + mi * 1024);                        \
    _Pragma("unroll") for (int nf = 0; nf < 8; ++nf)                                \
        fb[nf] = *(const short8*)((bbuf) + bfb + nf * 1024);                        \
} while (0)
#define MFMA_T(fa, fb) do {                                                         \
    __builtin_amdgcn_s_setprio(1);                                                  \
    _Pragma("unroll") for (int mi = 0; mi < 4; ++mi)                                \
    _Pragma("unroll") for (int nf = 0; nf < 8; ++nf)                                \
        acc[mi][nf] = __builtin_amdgcn_mfma_f32_16x16x32_bf16(                      \
            fa[mi], fb[nf], acc[mi][nf], 0, 0, 0);                                  \
    __builtin_amdgcn_s_setprio(0);                                                  \
} while (0)
// Per-tile: 1x VMW(0) (full-tile cover -> no stall), 1x LGKM0+BAR, then next-tile
// loads + frag reads fly under the 32-MFMA cluster. Race audit: B(t+2)->LDSB[par]
// is fenced from frag-reads of B(t) (issued pre-previous BAR) by this tile's BAR.
#define TILE(faP, fbP, faN, fbN, parbuf, npbuf, t) do {                             \
    VMW(0);                      /* A(t+1) regs + B(t+1) LDS landed */              \
    A_WRITE(npbuf);              /* A(t+1) -> LDS */                                \
    LGKM0(); BAR(); SB0();       /* frags(t) confirmed; npbuf published */          \
    { int k2_ = (((t) + 2) & 63) * 32; A_LOAD(k2_); B_GLD(parbuf, k2_); }           \
    FRAG_READ(faN, fbN, LDSA(npbuf), LDSB(npbuf));                                  \
    MFMA_T(faP, fbP);                                                               \
} while (0)

    f32x4 acc[4][8];
#pragma unroll
    for (int i = 0; i < 4; ++i)
#pragma unroll
        for (int j = 0; j < 8; ++j) acc[i][j] = (f32x4)0.0f;

    float4 stA;
    short8 fA0[4], fB0[8], fA1[4], fB1[8];

    // ---- prologue
    A_LOAD(0);                    // 1 vm
    B_GLD(0, 0);                  // 8 vm
    VMW(8);                       // A(0) ready
    A_WRITE(0);
    A_LOAD(32);                   // A(1)
    B_GLD(1, 32);                 // B(1)
    VMW(9);                       // B(0) landed; A(1)+B(1)=9 in flight
    LGKM0(); BAR(); SB0();
    FRAG_READ(fA0, fB0, LDSA(0), LDSB(0));

#pragma unroll 1
    for (int t = 0; t < 64; t += 2) {
        TILE(fA0, fB0, fA1, fB1, 0, 1, t);
        TILE(fA1, fB1, fA0, fB0, 1, 0, t + 1);
    }

    // ---- epilogue: bias+ReLU, LN stats, mask-pack, store
    VMW(0); LGKM0(); BAR(); SB0();         // drain tail junk; LDS reusable

    float* redS = (float*)LDS;             // [8][64]
    float* redQ = (float*)(LDS + 2048);    // [8][64]
    float* muT  = (float*)(LDS + 4096);    // [64]
    float* rsT  = (float*)(LDS + 4352);    // [64]

    float bb[8];
#pragma unroll
    for (int nf = 0; nf < 8; ++nf) bb[nf] = bias[w * 128 + nf * 16 + lrow];

    float s[4][4], q[4][4];
#pragma unroll
    for (int mi = 0; mi < 4; ++mi)
#pragma unroll
        for (int r = 0; r < 4; ++r) { s[mi][r] = 0.f; q[mi][r] = 0.f; }
#pragma unroll
    for (int mi = 0; mi < 4; ++mi)
#pragma unroll
        for (int nf = 0; nf < 8; ++nf)
#pragma unroll
            for (int r = 0; r < 4; ++r) {
                float v = fmaxf(acc[mi][nf][r] + bb[nf], 0.f);
                acc[mi][nf][r] = v;
                s[mi][r] += v;
                q[mi][r] += v * v;
            }
#pragma unroll
    for (int mi = 0; mi < 4; ++mi)
#pragma unroll
        for (int r = 0; r < 4; ++r)
#pragma unroll
            for (int off = 1; off <= 8; off <<= 1) {
                s[mi][r] += __shfl_xor(s[mi][r], off);
                q[mi][r] += __shfl_xor(q[mi][r], off);
            }
    if (lrow == 0) {
#pragma unroll
        for (int mi = 0; mi < 4; ++mi)
#pragma unroll
            for (int r = 0; r < 4; ++r) {
                int m = mi * 16 + lchk * 4 + r;
                redS[w * 64 + m] = s[mi][r];
                redQ[w * 64 + m] = q[mi][r];
            }
    }
    LGKM0(); BAR(); SB0();
    if (tid < 64) {
        float S = 0.f, Q = 0.f;
#pragma unroll
        for (int ww = 0; ww < 8; ++ww) { S += redS[ww * 64 + tid]; Q += redQ[ww * 64 + tid]; }
        float mu  = S * (1.0f / 1024.0f);
        float var = Q * (1.0f / 1024.0f) - mu * mu;
        muT[tid] = mu;
        rsT[tid] = rsqrtf(var + 1e-12f);
    }
    LGKM0(); BAR(); SB0();

    int mv = mask[(b << 6) | lane];
    unsigned long long bal = __ballot(mv != 0);
    int cnt = __popcll(bal);

    float lw[8], lb[8];
#pragma unroll
    for (int nf = 0; nf < 8; ++nf) {
        int col = w * 128 + nf * 16 + lrow;
        lw[nf] = lnw[col];
        lb[nf] = lnb[col];
    }
#pragma unroll
    for (int mi = 0; mi < 4; ++mi)
#pragma unroll
        for (int r = 0; r < 4; ++r) {
            int m = mi * 16 + lchk * 4 + r;
            if ((bal >> m) & 1ull) {
                int d = __popcll(bal & ((1ull << m) - 1ull));
                float mu = muT[m], rs = rsT[m];
                long obase = ((long)(b << 6) + d) * D_OUT + w * 128 + lrow;
#pragma unroll
                for (int nf = 0; nf < 8; ++nf)
                    out[obase + nf * 16] = (acc[mi][nf][r] - mu) * rs * lw[nf] + lb[nf];
            }
        }
    // zero the padded tail rows (full coverage: harness gets deterministic out)
    for (int d = cnt; d < 64; ++d) {
        float2 z = make_float2(0.f, 0.f);
        *(float2*)(out + ((long)(b << 6) + d) * D_OUT + w * 128 + lane * 2) = z;
    }
}

// ---------- launch ----------
extern "C" void kernel_launch(void* const* d_in, const int* in_sizes, int n_in,
                              void* d_out, int out_size, void* d_ws, size_t ws_size,
                              hipStream_t stream) {
    const float* img  = (const float*)d_in[0];
    const int*   mask = (const int*)d_in[2];
    const float* W    = (const float*)d_in[4];
    const float* bias = (const float*)d_in[5];
    const float* lnw  = (const float*)d_in[6];
    const float* lnb  = (const float*)d_in[7];
    float* out = (float*)d_out;

    short* Bt = (short*)d_ws;   // 4 MiB

    transpose_w_kernel<<<dim3(D_OUT / 32, D_IN / 32), 256, 0, stream>>>(W, Bt);
    fused_kernel<<<512, 512, 0, stream>>>(img, Bt, bias, mask, lnw, lnb, out);
}

// Round 7
// 281.293 us; speedup vs baseline: 1.1739x; 1.0053x over previous
//
#include <hip/hip_runtime.h>
#include <hip/hip_bf16.h>

// ---------- types ----------
typedef __attribute__((ext_vector_type(8))) short short8;   // 8 bf16 (4 VGPR)
typedef __attribute__((ext_vector_type(4))) short short4v;  // 4 bf16
typedef __attribute__((ext_vector_type(4))) float f32x4;

#define D_IN   2048
#define D_OUT  1024

__device__ __forceinline__ short f2bf(float x) {
    union { __hip_bfloat16 h; short s; } u;
    u.h = __float2bfloat16(x);
    return u.s;
}

// ---------- 1. W [2048][1024] f32 -> Bt [1024][2048] bf16 ----------
__global__ void transpose_w_kernel(const float* __restrict__ W,
                                   short* __restrict__ Bt) {
    __shared__ float tile[32][33];
    int c0 = blockIdx.x * 32;
    int r0 = blockIdx.y * 32;
    int tc = threadIdx.x & 31;
    int tr = threadIdx.x >> 5;
#pragma unroll
    for (int i = 0; i < 32; i += 8)
        tile[tr + i][tc] = W[(long)(r0 + tr + i) * D_OUT + c0 + tc];
    __syncthreads();
#pragma unroll
    for (int i = 0; i < 32; i += 8)
        Bt[(long)(c0 + tr + i) * D_IN + r0 + tc] = f2bf(tile[tc][tr + i]);
}

// ---------- 2. Fully-fused: GEMM(64x1024x2048) + bias + ReLU + LN + pack ----------
// One block = one image. 512 threads = 8 waves; wave w owns cols [w*128, +128).
// BK=32, 64 K-tiles. NO global_load_lds anywhere: B reg-staged (8 b128 gld +
// 8 swizzled ds_write_b128 per thread), A reg-staged f32->bf16 (1 gld + 1 b64).
// LDS 69632 B: B [1024 rows][64 B] at 0 (single-buffered, write-after-BAR),
//              A [64 rows][64 B] at 65536 (single-buffered, same proof).
// Atom swizzle both sides: slot(r,c) = c ^ (r&3) ^ ((r>>2)&3)  (16B atoms in a
// 64B row). Frag reads / ds_writes are uniform over bank slots (b128 floor).

#define BAR()    __builtin_amdgcn_s_barrier()
#define SB0()    __builtin_amdgcn_sched_barrier(0)
#define LGKM0()  do { asm volatile("s_waitcnt lgkmcnt(0)" ::: "memory"); SB0(); } while (0)

__global__ __launch_bounds__(512, 2)
void fused_kernel(const float* __restrict__ img, const short* __restrict__ Bt,
                  const float* __restrict__ bias, const int* __restrict__ mask,
                  const float* __restrict__ lnw, const float* __restrict__ lnb,
                  float* __restrict__ out) {
    __shared__ char LDS[69632];

    const int b    = blockIdx.x;
    const int tid  = threadIdx.x;
    const int lane = tid & 63;
    const int w    = tid >> 6;
    const int lrow = lane & 15;
    const int lchk = lane >> 4;    // k-chunk 0..3

    // B staging: thread handles rows r = (tid>>2)+j*128 (j=0..7), chunk c=tid&3.
    const int brow = tid >> 2;
    const int bchk = tid & 3;
    const int bswz = bchk ^ (brow & 3) ^ ((tid >> 4) & 3);   // (r>>2)&3 == (tid>>4)&3 for all j
    const short* bsrc = Bt + (long)brow * D_IN + bchk * 8;
    char* bdst = LDS + brow * 64 + bswz * 16;                // + j*8192
    // A staging: row arl = tid>>3, 4 f32 k-elems at (tid&7)*4; half-atom write.
    const int arl   = tid >> 3;
    const long arowg = (long)b * 64 + arl;
    const int ak4   = (tid & 7) * 4;
    const int achk  = (tid & 7) >> 1;
    char* adst = LDS + 65536 + arl * 64
               + ((achk ^ (arl & 3) ^ ((arl >> 2) & 3)) * 16) + (tid & 1) * 8;
    // frag-read bases (swizzle identical to write side; mi/nf offsets are +1024
    // multiples which never touch the swizzled bits)
    const int fsw = ((lchk ^ (lrow & 3) ^ ((lrow >> 2) & 3)) << 4);
    const char* afb = LDS + 65536 + lrow * 64 + fsw;
    const char* bfb = LDS + w * 8192 + lrow * 64 + fsw;

    f32x4 acc[4][8];
#pragma unroll
    for (int i = 0; i < 4; ++i)
#pragma unroll
        for (int j = 0; j < 8; ++j) acc[i][j] = (f32x4)0.0f;

    short8 bst[8];
    float4 stA;
    short8 fa[4], fb[8];

    // ---- prologue: issue tile-0 loads (waited by compiler vmcnt at first use)
    stA = *(const float4*)(img + arowg * D_IN + ak4);
#pragma unroll
    for (int j = 0; j < 8; ++j)
        bst[j] = *(const short8*)(bsrc + (long)j * 128 * D_IN);

#pragma unroll 1
    for (int t = 0; t < 64; ++t) {
        // ---- BAR1: everyone's frag reads of tile t-1 are consumed (MFMA
        //      waited them) -> LDS overwritable
        BAR(); SB0();
        // write tile t (compiler inserts vmcnt before first bst/stA use)
        {
            short4v ca;
            ca[0] = f2bf(stA.x); ca[1] = f2bf(stA.y);
            ca[2] = f2bf(stA.z); ca[3] = f2bf(stA.w);
            *(short4v*)adst = ca;
        }
#pragma unroll
        for (int j = 0; j < 8; ++j)
            *(short8*)(bdst + j * 8192) = bst[j];
        // issue tile t+1 loads (anti-dep on writes keeps order; in flight
        // across the rest of the tile = full-tile latency cover)
        {
            int k1 = ((t + 1) & 63) * 32;
            stA = *(const float4*)(img + arowg * D_IN + k1 + ak4);
#pragma unroll
            for (int j = 0; j < 8; ++j)
                bst[j] = *(const short8*)(bsrc + (long)j * 128 * D_IN + k1);
        }
        LGKM0();                 // ds_writes drained (raw s_barrier doesn't wait)
        BAR(); SB0();            // ---- BAR2: tile t published
        // frag reads + MFMA: compiler emits fine-grained lgkmcnt per MFMA
#pragma unroll
        for (int mi = 0; mi < 4; ++mi)
            fa[mi] = *(const short8*)(afb + mi * 1024);
#pragma unroll
        for (int nf = 0; nf < 8; ++nf)
            fb[nf] = *(const short8*)(bfb + nf * 1024);
        __builtin_amdgcn_s_setprio(1);
#pragma unroll
        for (int mi = 0; mi < 4; ++mi)
#pragma unroll
            for (int nf = 0; nf < 8; ++nf)
                acc[mi][nf] = __builtin_amdgcn_mfma_f32_16x16x32_bf16(
                    fa[mi], fb[nf], acc[mi][nf], 0, 0, 0);
        __builtin_amdgcn_s_setprio(0);
    }

    // ---- epilogue: bias+ReLU, LN stats, mask-pack, store (R6-verified)
    __syncthreads();                       // all MFMA/ds done; LDS reusable

    float* redS = (float*)LDS;             // [8][64]
    float* redQ = (float*)(LDS + 2048);    // [8][64]
    float* muT  = (float*)(LDS + 4096);    // [64]
    float* rsT  = (float*)(LDS + 4352);    // [64]

    float bb[8];
#pragma unroll
    for (int nf = 0; nf < 8; ++nf) bb[nf] = bias[w * 128 + nf * 16 + lrow];

    float s[4][4], q[4][4];
#pragma unroll
    for (int mi = 0; mi < 4; ++mi)
#pragma unroll
        for (int r = 0; r < 4; ++r) { s[mi][r] = 0.f; q[mi][r] = 0.f; }
#pragma unroll
    for (int mi = 0; mi < 4; ++mi)
#pragma unroll
        for (int nf = 0; nf < 8; ++nf)
#pragma unroll
            for (int r = 0; r < 4; ++r) {
                float v = fmaxf(acc[mi][nf][r] + bb[nf], 0.f);
                acc[mi][nf][r] = v;
                s[mi][r] += v;
                q[mi][r] += v * v;
            }
#pragma unroll
    for (int mi = 0; mi < 4; ++mi)
#pragma unroll
        for (int r = 0; r < 4; ++r)
#pragma unroll
            for (int off = 1; off <= 8; off <<= 1) {
                s[mi][r] += __shfl_xor(s[mi][r], off);
                q[mi][r] += __shfl_xor(q[mi][r], off);
            }
    if (lrow == 0) {
#pragma unroll
        for (int mi = 0; mi < 4; ++mi)
#pragma unroll
            for (int r = 0; r < 4; ++r) {
                int m = mi * 16 + lchk * 4 + r;
                redS[w * 64 + m] = s[mi][r];
                redQ[w * 64 + m] = q[mi][r];
            }
    }
    __syncthreads();
    if (tid < 64) {
        float S = 0.f, Q = 0.f;
#pragma unroll
        for (int ww = 0; ww < 8; ++ww) { S += redS[ww * 64 + tid]; Q += redQ[ww * 64 + tid]; }
        float mu  = S * (1.0f / 1024.0f);
        float var = Q * (1.0f / 1024.0f) - mu * mu;
        muT[tid] = mu;
        rsT[tid] = rsqrtf(var + 1e-12f);
    }
    __syncthreads();

    int mv = mask[(b << 6) | lane];
    unsigned long long bal = __ballot(mv != 0);
    int cnt = __popcll(bal);

    float lw[8], lb[8];
#pragma unroll
    for (int nf = 0; nf < 8; ++nf) {
        int col = w * 128 + nf * 16 + lrow;
        lw[nf] = lnw[col];
        lb[nf] = lnb[col];
    }
#pragma unroll
    for (int mi = 0; mi < 4; ++mi)
#pragma unroll
        for (int r = 0; r < 4; ++r) {
            int m = mi * 16 + lchk * 4 + r;
            if ((bal >> m) & 1ull) {
                int d = __popcll(bal & ((1ull << m) - 1ull));
                float mu = muT[m], rs = rsT[m];
                long obase = ((long)(b << 6) + d) * D_OUT + w * 128 + lrow;
#pragma unroll
                for (int nf = 0; nf < 8; ++nf)
                    out[obase + nf * 16] = (acc[mi][nf][r] - mu) * rs * lw[nf] + lb[nf];
            }
        }
    // zero the padded tail rows (deterministic full coverage of d_out)
    for (int d = cnt; d < 64; ++d) {
        float2 z = make_float2(0.f, 0.f);
        *(float2*)(out + ((long)(b << 6) + d) * D_OUT + w * 128 + lane * 2) = z;
    }
}

// ---------- launch ----------
extern "C" void kernel_launch(void* const* d_in, const int* in_sizes, int n_in,
                              void* d_out, int out_size, void* d_ws, size_t ws_size,
                              hipStream_t stream) {
    const float* img  = (const float*)d_in[0];
    const int*   mask = (const int*)d_in[2];
    const float* W    = (const float*)d_in[4];
    const float* bias = (const float*)d_in[5];
    const float* lnw  = (const float*)d_in[6];
    const float* lnb  = (const float*)d_in[7];
    float* out = (float*)d_out;

    short* Bt = (short*)d_ws;   // 4 MiB

    transpose_w_kernel<<<dim3(D_OUT / 32, D_IN / 32), 256, 0, stream>>>(W, Bt);
    fused_kernel<<<512, 512, 0, stream>>>(img, Bt, bias, mask, lnw, lnb, out);
}